// Round 5
// baseline (240.499 us; speedup 1.0000x reference)
//
#include <hip/hip_runtime.h>

// ---------------------------------------------------------------------------
// MSAAttention fused pipeline (MI355X / gfx950), bf16 MFMA throughout.
//
// out = concat[softmax(qk^T*s)v @ w_merge + b_merge, ib] @ w_proj + b_proj
// Folded: wcombT = [(w_merge@w_proj_top)^T | w_proj_bot^T]; merge GEMM deleted;
// biasc = b_merge@w_proj_top + b_proj. SCALE*log2e folded into q; softmax in
// exp2 domain, no max-subtraction (logits bounded ~1).
//
// All hot staging uses global_load_lds (16B DMA) with XOR-permuted SOURCE
// addressing: LDS rows are 128 B of 8 granules, granule g of row r lands in
// slot g^(r&7), so b128 frag reads (lane pattern row=c, granule fixed) hit
// all bank quads with only c/c+8 2-way aliasing (free per m136). No padding
// => compatible with GLDS's uniform-base+lane*16 write rule.
// attn: KV-tile 64, K+V dbuf GLDS, ONE barrier/iter; V read from globally
// pre-transposed vT (written by the qkv GEMM epilogue); l via ones-MFMA.
// 512-thr blocks, 41.5 KB LDS -> 16 waves/CU.
// ---------------------------------------------------------------------------

typedef unsigned short u16;
typedef unsigned int u32;
typedef __bf16 bf16x8 __attribute__((ext_vector_type(8)));
typedef u16 su16x8 __attribute__((ext_vector_type(8)));
typedef u16 su16x4 __attribute__((ext_vector_type(4)));
typedef u32 u32x4 __attribute__((ext_vector_type(4)));
typedef float f32x4 __attribute__((ext_vector_type(4)));

__device__ __forceinline__ u16 f2bf(float f) {
  union { __bf16 h; u16 u; } v;
  v.h = (__bf16)f;
  return v.u;
}

__device__ __forceinline__ float fexp2(float x) {
#if __has_builtin(__builtin_amdgcn_exp2f)
  return __builtin_amdgcn_exp2f(x);
#else
  return __expf(x * 0.6931471805599453f);
#endif
}

__device__ __forceinline__ f32x4 zero4() {
  f32x4 v = {0.f, 0.f, 0.f, 0.f};
  return v;
}

__device__ __forceinline__ f32x4 mfma16(bf16x8 a, bf16x8 b, f32x4 c) {
  return __builtin_amdgcn_mfma_f32_16x16x32_bf16(a, b, c, 0, 0, 0);
}

// async 16B/lane global->LDS DMA; LDS dest = wave-uniform base + lane*16
#define GLDS(gp, lp)                                             \
  __builtin_amdgcn_global_load_lds(                              \
      (const __attribute__((address_space(1))) u32*)(gp),        \
      (__attribute__((address_space(3))) u32*)(lp), 16, 0, 0)

// ---------------------------------------------------------------------------
// fused_prep (736 blocks):
//   [0,96)   : wqkvT[1536][256] transpose-convert of w_qkv
//   [96,128) : wcombT[:,512+]   transpose-convert of w_proj_bot
//   [128,192): wcombT[:,:512] = (w_merge @ w_proj_top)^T  (bf16 mfma, raw f32 in)
//   [192,224): biasc = b_proj + b_merge @ w_proj_top
//   [224,736): ib branch: x -> bf16 xb AND [16,16] linear-SiLU-linear -> catb
// ---------------------------------------------------------------------------
__global__ __launch_bounds__(256) void fused_prep(
    const float* __restrict__ x, const float* __restrict__ w_qkv,
    const float* __restrict__ w_merge, const float* __restrict__ w_proj,
    const float* __restrict__ b_merge, const float* __restrict__ b_proj,
    const float* __restrict__ w_in, const float* __restrict__ b_in,
    const float* __restrict__ w_out, const float* __restrict__ b_out,
    u16* __restrict__ wqkvT, u16* __restrict__ wcombT,
    float* __restrict__ biasc, u16* __restrict__ xb, u16* __restrict__ catb) {
  __shared__ __align__(16) char SM[35456];
  int blk = blockIdx.x, tid = threadIdx.x;
  if (blk >= 224) {
    // ---------------- ib branch ----------------
    float* wi = (float*)SM;
    float* wo = wi + 256;
    float* bi = wo + 256;
    float* bo = bi + 16;
    float* xs = (float*)(SM + 2176);   // 16*260
    float* hs = (float*)(SM + 18816);  // 16*260
    int b2 = blk - 224;
    wi[tid] = w_in[tid];
    wo[tid] = w_out[tid];
    if (tid < 16) { bi[tid] = b_in[tid]; bo[tid] = b_out[tid]; }
    size_t blkoff = (size_t)b2 * 4096;
#pragma unroll
    for (int i = 0; i < 4; ++i) {
      int f = (tid + i * 256) * 4;
      float4 v = *(const float4*)&x[blkoff + f];
      int tok = f >> 8, p = f & 255;
      *(float4*)&xs[tok * 260 + p] = v;
      su16x4 pk = {f2bf(v.x), f2bf(v.y), f2bf(v.z), f2bf(v.w)};
      *(su16x4*)&xb[blkoff + f] = pk;
    }
    __syncthreads();
    int t = tid >> 4, p2 = tid & 15;
#pragma unroll
    for (int p1 = 0; p1 < 16; ++p1) {
      float a = bi[p2];
#pragma unroll
      for (int k = 0; k < 16; ++k)
        a += xs[t * 260 + p1 * 16 + k] * wi[k * 16 + p2];
      hs[t * 260 + p1 * 16 + p2] = a / (1.f + __expf(-a));
    }
    __syncthreads();
    size_t tok = (size_t)b2 * 16 + t;
#pragma unroll
    for (int p1 = 0; p1 < 16; ++p1) {
      float o = bo[p2];
#pragma unroll
      for (int j = 0; j < 16; ++j)
        o += hs[t * 260 + p1 * 16 + j] * wo[j * 16 + p2];
      catb[tok * 768 + 512 + p1 * 16 + p2] = f2bf(o);
    }
    return;
  }
  if (blk < 128) {
    // ---------------- transpose-convert branches ----------------
    const float* src;
    int lsrc, ldd, r0, c0;
    u16* dst;
    if (blk < 96) {
      src = w_qkv; lsrc = 1536; dst = wqkvT; ldd = 256;
      r0 = (blk & 3) * 64; c0 = (blk >> 2) * 64;
    } else {
      int b2 = blk - 96;
      src = w_proj + 512 * 512; lsrc = 512; dst = wcombT + 512; ldd = 768;
      r0 = (b2 & 3) * 64; c0 = (b2 >> 2) * 64;
    }
    u16* Ts = (u16*)SM;  // 64*68
    int rr = tid >> 4, cc4 = (tid & 15) * 4;
#pragma unroll
    for (int rep = 0; rep < 4; ++rep) {
      int r = rr + rep * 16;
      float4 v = *(const float4*)&src[(size_t)(r0 + r) * lsrc + c0 + cc4];
      su16x4 pk = {f2bf(v.x), f2bf(v.y), f2bf(v.z), f2bf(v.w)};
      *(su16x4*)&Ts[r * 68 + cc4] = pk;
    }
    __syncthreads();
    int c = tid & 63, seg = tid >> 6;
    __align__(16) u16 tmp[16];
#pragma unroll
    for (int k = 0; k < 16; ++k) tmp[k] = Ts[(seg * 16 + k) * 68 + c];
    *(su16x8*)&dst[(size_t)(c0 + c) * ldd + r0 + seg * 16] = *(su16x8*)tmp;
    *(su16x8*)&dst[(size_t)(c0 + c) * ldd + r0 + seg * 16 + 8] =
        *(su16x8*)(tmp + 8);
  } else if (blk < 192) {
    // ---------------- wcombT top = (w_merge @ w_proj_top)^T ----------------
    // C[n][m] = sum_k w_proj[k][n] * w_merge[m][k]; 64x64 tile, K=512.
    int b2 = blk - 128;
    int n0 = (b2 & 7) * 64, m0 = (b2 >> 3) * 64;
    u16* As = (u16*)SM;            // [64 n][40]
    u16* Bs = (u16*)(SM + 5120);   // [64 m][40]
    int lane = tid & 63, wave = tid >> 6;
    int c = lane & 15, g4 = lane >> 4;
    int wm = (wave >> 1) * 32, wn = (wave & 1) * 32;
    f32x4 acc2[2][2];
#pragma unroll
    for (int a = 0; a < 2; ++a)
#pragma unroll
      for (int b = 0; b < 2; ++b) acc2[a][b] = zero4();
    for (int k0 = 0; k0 < 512; k0 += 32) {
      __syncthreads();
      {  // A: transpose-convert w_proj[k0..+32][n0..+64]
        int kk = tid >> 3, nn0 = (tid & 7) * 8;
        const float* sp = &w_proj[(size_t)(k0 + kk) * 512 + n0 + nn0];
        float4 v0 = *(const float4*)sp;
        float4 v1 = *(const float4*)(sp + 4);
        As[(nn0 + 0) * 40 + kk] = f2bf(v0.x);
        As[(nn0 + 1) * 40 + kk] = f2bf(v0.y);
        As[(nn0 + 2) * 40 + kk] = f2bf(v0.z);
        As[(nn0 + 3) * 40 + kk] = f2bf(v0.w);
        As[(nn0 + 4) * 40 + kk] = f2bf(v1.x);
        As[(nn0 + 5) * 40 + kk] = f2bf(v1.y);
        As[(nn0 + 6) * 40 + kk] = f2bf(v1.z);
        As[(nn0 + 7) * 40 + kk] = f2bf(v1.w);
      }
      {  // B: convert w_merge rows
        int mm = tid >> 2, kk0 = (tid & 3) * 8;
        const float* sp = &w_merge[(size_t)(m0 + mm) * 512 + k0 + kk0];
        float4 v0 = *(const float4*)sp;
        float4 v1 = *(const float4*)(sp + 4);
        su16x4 p0 = {f2bf(v0.x), f2bf(v0.y), f2bf(v0.z), f2bf(v0.w)};
        su16x4 p1 = {f2bf(v1.x), f2bf(v1.y), f2bf(v1.z), f2bf(v1.w)};
        *(su16x4*)&Bs[mm * 40 + kk0] = p0;
        *(su16x4*)&Bs[mm * 40 + kk0 + 4] = p1;
      }
      __syncthreads();
      bf16x8 af[2], bf[2];
#pragma unroll
      for (int mt = 0; mt < 2; ++mt)
        af[mt] = *(const bf16x8*)&As[(wm + mt * 16 + c) * 40 + g4 * 8];
#pragma unroll
      for (int nt = 0; nt < 2; ++nt)
        bf[nt] = *(const bf16x8*)&Bs[(wn + nt * 16 + c) * 40 + g4 * 8];
#pragma unroll
      for (int mt = 0; mt < 2; ++mt)
#pragma unroll
        for (int nt = 0; nt < 2; ++nt)
          acc2[mt][nt] = mfma16(af[mt], bf[nt], acc2[mt][nt]);
    }
#pragma unroll
    for (int mt = 0; mt < 2; ++mt)
#pragma unroll
      for (int nt = 0; nt < 2; ++nt)
#pragma unroll
        for (int i = 0; i < 4; ++i)
          wcombT[(size_t)(n0 + wm + mt * 16 + g4 * 4 + i) * 768 + m0 + wn +
                 nt * 16 + c] = f2bf(acc2[mt][nt][i]);
  } else {
    // ---------------- biasc ----------------
    int col0 = (blk - 192) * 16;
    float* red = (float*)SM;  // [16][17]
    int kr = tid >> 4, cc = tid & 15;
    float s = 0.f;
#pragma unroll 4
    for (int j = 0; j < 32; ++j) {
      int k = kr + j * 16;
      s += b_merge[k] * w_proj[(size_t)k * 512 + col0 + cc];
    }
    red[kr * 17 + cc] = s;
    __syncthreads();
    if (kr == 0) {
      float a = b_proj[col0 + cc];
#pragma unroll
      for (int t = 0; t < 16; ++t) a += red[t * 17 + cc];
      biasc[col0 + cc] = a;
    }
  }
}

// ---------------------------------------------------------------------------
// gemm64: C[128 x 64 tile] = A[m][k] @ BT[n][k]^T. BK=64, XOR-GLDS staging,
// dbuf, ONE barrier per K-iter. Waves 2x2 (wave tile 64x32).
// OUTMODE 0: f32 out (+bias). OUTMODE 1 (qkv): bf16; cols<512 scaled by
// SCALE*log2e -> qkb; cols>=1024 written TRANSPOSED to vT[b][h][d][tok].
// ---------------------------------------------------------------------------
template <int OUTMODE>
__global__ __launch_bounds__(256, 3) void gemm64(
    const u16* __restrict__ A, int lda, const u16* __restrict__ BT, int ldb,
    int kcount, const float* __restrict__ bias, void* __restrict__ Co, int ldc,
    u16* __restrict__ vTout) {
  constexpr int TM = 128, TN = 64;
  constexpr int ROWS = TM + TN;       // 192 rows x 128 B
  constexpr int BUFU = ROWS * 64;     // 12288 u16 per buffer
  __shared__ __align__(16) u16 S[2 * BUFU];  // 49152 B
  int tid = threadIdx.x, lane = tid & 63, wave = tid >> 6;
  int c = lane & 15, g4 = lane >> 4;
  int m0 = blockIdx.y * TM, n0 = blockIdx.x * TN;
  int wm = (wave >> 1) * 64, wn = (wave & 1) * 32;
  int lr = lane >> 3, lg = lane & 7;
  f32x4 acc[4][2];
#pragma unroll
  for (int a = 0; a < 4; ++a)
#pragma unroll
    for (int b = 0; b < 2; ++b) acc[a][b] = zero4();

  auto stage = [&](int kb, int bsel) {
#pragma unroll
    for (int t = 0; t < 6; ++t) {
      int chunk = wave * 6 + t;
      int row = chunk * 8 + lr;
      int gs = lg ^ lr;
      const u16* gp = row < TM
                          ? &A[(size_t)(m0 + row) * lda + kb + gs * 8]
                          : &BT[(size_t)(n0 + row - TM) * ldb + kb + gs * 8];
      GLDS(gp, &S[bsel * BUFU + chunk * 512]);
    }
  };
  stage(0, 0);
  int nIter = kcount >> 6;
  for (int it = 0; it < nIter; ++it) {
    int bsel = it & 1;
    __syncthreads();  // drains DMA(it); prev compute done
    if (it + 1 < nIter) stage((it + 1) << 6, bsel ^ 1);
    bf16x8 af[4][2], bf[2][2];
#pragma unroll
    for (int ks = 0; ks < 2; ++ks) {
#pragma unroll
      for (int mt = 0; mt < 4; ++mt)
        af[mt][ks] = *(const bf16x8*)&S[bsel * BUFU + (wm + mt * 16 + c) * 64 +
                                        ((ks * 4 + g4) ^ (c & 7)) * 8];
#pragma unroll
      for (int nt = 0; nt < 2; ++nt)
        bf[nt][ks] =
            *(const bf16x8*)&S[bsel * BUFU + (TM + wn + nt * 16 + c) * 64 +
                               ((ks * 4 + g4) ^ (c & 7)) * 8];
    }
#pragma unroll
    for (int ks = 0; ks < 2; ++ks)
#pragma unroll
      for (int mt = 0; mt < 4; ++mt)
#pragma unroll
        for (int nt = 0; nt < 2; ++nt)
          acc[mt][nt] = mfma16(af[mt][ks], bf[nt][ks], acc[mt][nt]);
  }

  if (OUTMODE == 0) {
    float* Cf = (float*)Co;
#pragma unroll
    for (int nt = 0; nt < 2; ++nt) {
      int col = n0 + wn + nt * 16 + c;
      float bv = bias ? bias[col] : 0.f;
#pragma unroll
      for (int mt = 0; mt < 4; ++mt)
#pragma unroll
        for (int i = 0; i < 4; ++i)
          Cf[(size_t)(m0 + wm + mt * 16 + g4 * 4 + i) * ldc + col] =
              acc[mt][nt][i] + bv;
    }
  } else {
    u16* C16 = (u16*)Co;
    u16* Cs = S;  // [64][72] per half
    __syncthreads();
#pragma unroll
    for (int half = 0; half < 2; ++half) {
      if ((wave >> 1) == half) {
#pragma unroll
        for (int nt = 0; nt < 2; ++nt) {
          int col = n0 + wn + nt * 16 + c;
          float bv = bias ? bias[col] : 0.f;
          float sc = (col < 512) ? 0.18033688011112042f : 1.f;
#pragma unroll
          for (int mt = 0; mt < 4; ++mt)
#pragma unroll
            for (int i = 0; i < 4; ++i)
              Cs[(mt * 16 + g4 * 4 + i) * 72 + wn + nt * 16 + c] =
                  f2bf((acc[mt][nt][i] + bv) * sc);
        }
      }
      __syncthreads();
      if (n0 < 1024) {  // q|k -> qkb rows (b128 stores)
        int row = tid >> 2;
#pragma unroll
        for (int t = 0; t < 2; ++t) {
          int gr = (tid & 3) + t * 4;
          u32x4 v = *(const u32x4*)&Cs[row * 72 + gr * 8];
          *(u32x4*)&C16[(size_t)(m0 + half * 64 + row) * ldc + n0 + gr * 8] = v;
        }
      } else {  // v -> vT[b][h][d][tok] transposed
        int d = tid >> 2, tr = (tid & 3) * 16;
        __align__(16) u16 tmp[16];
#pragma unroll
        for (int j = 0; j < 16; ++j) tmp[j] = Cs[(tr + j) * 72 + d];
        int b = m0 >> 11, h = (n0 - 1024) >> 6;
        size_t vaddr = ((size_t)((b * 8 + h) * 64 + d)) * 2048 + (m0 & 2047) +
                       half * 64 + tr;
        *(su16x8*)&vTout[vaddr] = *(su16x8*)tmp;
        *(su16x8*)&vTout[vaddr + 8] = *(su16x8*)(tmp + 8);
      }
      __syncthreads();
    }
  }
}

// ---------------------------------------------------------------------------
// attn_kernel: flash attention, exp2 domain, no running max.
// 512 thr = 8 waves = 4 q-groups x 2 kv-halves; wave = 32q x 32kv per iter.
// KV-tile 64; K and V both XOR-GLDS double-buffered; ONE barrier per iter
// (P region is wave-private -> in-wave DS ordering suffices).
// S^T = K·Q^T -> packed b64 P writes -> b128 A-frags; l via ones-MFMA.
// LDS 41472 B. Grid 512 = (qt 0..15) x (bh 0..31).
// ---------------------------------------------------------------------------
__global__ __launch_bounds__(512, 4) void attn_kernel(
    const u16* __restrict__ qkb, const u16* __restrict__ vT,
    u16* __restrict__ catb) {
  __shared__ __align__(16) u16 SMu[20736];
  u16* Ks = SMu;            // 2 x [64 kv][64 d]
  u16* Vs = SMu + 8192;     // 2 x [64 d][64 kv]
  u16* Ps = SMu + 16384;    // 8 waves x [16 q][34]
  int tid = threadIdx.x, lane = tid & 63, wave = tid >> 6;
  int c = lane & 15, g4 = lane >> 4;
  int qg = wave >> 1, kvh = wave & 1;
  int bh = blockIdx.x & 31, qt = blockIdx.x >> 5;
  int bb = bh >> 3, h = bh & 7;
  size_t kbase = (size_t)bb * 2048 * 1024;
  size_t vbase = (size_t)((bb * 8 + h) * 64) * 2048;
  u16* Psw = Ps + wave * 544;
  int lr = lane >> 3, lg = lane & 7;

  union { su16x8 u; bf16x8 b; } one_;
#pragma unroll
  for (int j = 0; j < 8; ++j) one_.u[j] = 0x3F80;
  bf16x8 onesb = one_.b;

  // Q frags (pre-scaled by SCALE*log2e in qkv epilogue)
  bf16x8 qf[2][2];
#pragma unroll
  for (int qh = 0; qh < 2; ++qh)
#pragma unroll
    for (int ks2 = 0; ks2 < 2; ++ks2) {
      int n = qt * 128 + qg * 32 + qh * 16 + c;
      qf[qh][ks2] = *(const bf16x8*)&qkb[kbase + (size_t)n * 1024 + h * 64 +
                                         ks2 * 32 + g4 * 8];
    }
  f32x4 oacc[2][4], lacc[2];
#pragma unroll
  for (int a = 0; a < 2; ++a) {
    lacc[a] = zero4();
#pragma unroll
    for (int b = 0; b < 4; ++b) oacc[a][b] = zero4();
  }

  auto stageK = [&](int n0k, int bsel) {
    int kv = wave * 8 + lr;
    const u16* gp = &qkb[kbase + (size_t)(n0k + kv) * 1024 + 512 + h * 64 +
                         (lg ^ lr) * 8];
    GLDS(gp, &Ks[bsel * 4096 + wave * 512]);
  };
  auto stageV = [&](int n0k, int bsel) {
    int d = wave * 8 + lr;
    const u16* gp = &vT[vbase + (size_t)d * 2048 + n0k + (lg ^ lr) * 8];
    GLDS(gp, &Vs[bsel * 4096 + wave * 512]);
  };
  stageK(0, 0);
  stageV(0, 0);

  for (int it = 0; it < 32; ++it) {
    int bsel = it & 1;
    __syncthreads();  // drains DMA(it); all waves done with buf bsel^1
    if (it < 31) {
      stageK((it + 1) * 64, bsel ^ 1);
      stageV((it + 1) * 64, bsel ^ 1);
    }
    // ---- S^T = K·Q^T over this wave's 32-kv half ----
    f32x4 sacc[2][2];
#pragma unroll
    for (int a = 0; a < 2; ++a)
#pragma unroll
      for (int b = 0; b < 2; ++b) sacc[a][b] = zero4();
#pragma unroll
    for (int ks2 = 0; ks2 < 2; ++ks2)
#pragma unroll
      for (int kvt = 0; kvt < 2; ++kvt) {
        bf16x8 kf = *(const bf16x8*)&Ks[bsel * 4096 +
                                        (kvh * 32 + kvt * 16 + c) * 64 +
                                        ((ks2 * 4 + g4) ^ (c & 7)) * 8];
        sacc[0][kvt] = mfma16(kf, qf[0][ks2], sacc[0][kvt]);
        sacc[1][kvt] = mfma16(kf, qf[1][ks2], sacc[1][kvt]);
      }
    // ---- P = exp2(S); b64 packed writes (wave-private); l via ones-MFMA ----
    bf16x8 pf[2];
#pragma unroll
    for (int qh = 0; qh < 2; ++qh) {
#pragma unroll
      for (int kvt = 0; kvt < 2; ++kvt) {
        float p0 = fexp2(sacc[qh][kvt][0]);
        float p1 = fexp2(sacc[qh][kvt][1]);
        float p2 = fexp2(sacc[qh][kvt][2]);
        float p3 = fexp2(sacc[qh][kvt][3]);
        su16x4 pk = {f2bf(p0), f2bf(p1), f2bf(p2), f2bf(p3)};
        *(su16x4*)&Psw[c * 34 + kvt * 16 + g4 * 4] = pk;
      }
      pf[qh] = *(const bf16x8*)&Psw[c * 34 + g4 * 8];
      lacc[qh] = mfma16(pf[qh], onesb, lacc[qh]);
    }
    // ---- O += P @ V ----
#pragma unroll
    for (int nt = 0; nt < 4; ++nt) {
      int d = nt * 16 + c;
      bf16x8 vf = *(const bf16x8*)&Vs[bsel * 4096 + d * 64 +
                                      ((kvh * 4 + g4) ^ (c & 7)) * 8];
      oacc[0][nt] = mfma16(pf[0], vf, oacc[0][nt]);
      oacc[1][nt] = mfma16(pf[1], vf, oacc[1][nt]);
    }
  }

  // ---- cross-kv-half reduction + store ----
  __syncthreads();
  float* ob = (float*)SMu;                    // [128][68] f32
  float* lb = (float*)(SMu + 17408);          // [128] f32 (byte 34816)
  if (kvh == 1) {
#pragma unroll
    for (int qh = 0; qh < 2; ++qh) {
      int qr = qg * 32 + qh * 16 + g4 * 4;
#pragma unroll
      for (int nt = 0; nt < 4; ++nt)
#pragma unroll
        for (int i = 0; i < 4; ++i)
          ob[(qr + i) * 68 + nt * 16 + c] = oacc[qh][nt][i];
      if (c == 0)
#pragma unroll
        for (int i = 0; i < 4; ++i) lb[qr + i] = lacc[qh][i];
    }
  }
  __syncthreads();
  if (kvh == 0) {
#pragma unroll
    for (int qh = 0; qh < 2; ++qh) {
      int qr = qg * 32 + qh * 16 + g4 * 4;
      float linv[4];
#pragma unroll
      for (int i = 0; i < 4; ++i)
        linv[i] = 1.f / (lacc[qh][i] + lb[qr + i]);
#pragma unroll
      for (int nt = 0; nt < 4; ++nt)
#pragma unroll
        for (int i = 0; i < 4; ++i) {
          int n = qt * 128 + qr + i;
          catb[(size_t)(bb * 2048 + n) * 768 + h * 64 + nt * 16 + c] =
              f2bf((oacc[qh][nt][i] + ob[(qr + i) * 68 + nt * 16 + c]) *
                   linv[i]);
        }
    }
  }
}

// ---------------------------------------------------------------------------
extern "C" void kernel_launch(void* const* d_in, const int* in_sizes, int n_in,
                              void* d_out, int out_size, void* d_ws,
                              size_t ws_size, hipStream_t stream) {
  const float* x = (const float*)d_in[0];
  const float* w_qkv = (const float*)d_in[1];
  const float* b_qkv = (const float*)d_in[2];
  const float* w_in = (const float*)d_in[3];
  const float* b_in = (const float*)d_in[4];
  const float* w_out = (const float*)d_in[5];
  const float* b_out = (const float*)d_in[6];
  const float* w_merge = (const float*)d_in[7];
  const float* b_merge = (const float*)d_in[8];
  const float* w_proj = (const float*)d_in[9];
  const float* b_proj = (const float*)d_in[10];

  char* ws = (char*)d_ws;
  u16* xb = (u16*)(ws + 0);                //  4,194,304 B  [8192][256]
  u16* qkb = (u16*)(ws + 4194304);         // 16,777,216 B  [8192][1024] q|k
  u16* vT = (u16*)(ws + 20971520);         //  8,388,608 B  [4][8][64][2048]
  u16* catb = (u16*)(ws + 29360128);       // 12,582,912 B  [8192][768]
  u16* wqkvT = (u16*)(ws + 41943040);      //    786,432 B  [1536][256]
  u16* wcombT = (u16*)(ws + 42729472);     //    786,432 B  [512][768]
  float* biasc = (float*)(ws + 43515904);  //      2,048 B

  fused_prep<<<736, 256, 0, stream>>>(x, w_qkv, w_merge, w_proj, b_merge,
                                      b_proj, w_in, b_in, w_out, b_out, wqkvT,
                                      wcombT, biasc, xb, catb);
  // qkv = x @ w_qkv + b_qkv; q scaled; k -> qkb cols 512..1023; v -> vT
  gemm64<1><<<dim3(24, 64), 256, 0, stream>>>(xb, 256, wqkvT, 256, 256, b_qkv,
                                              (void*)qkb, 1024, vT);
  attn_kernel<<<512, 512, 0, stream>>>(qkb, vT, catb);
  // out = catb @ wcombT^T + biasc  (fp32)
  gemm64<0><<<dim3(8, 64), 256, 0, stream>>>(catb, 768, wcombT, 768, 768,
                                             biasc, d_out, 512, nullptr);
}